// Round 13
// baseline (175.281 us; speedup 1.0000x reference)
//
#include <hip/hip_runtime.h>
#include <hip/hip_bf16.h>

#define S_LEN 2048
#define DIM   64
#define NBH   32            // B*H
#define NQT   32            // kv tiles of 64
#define NQB   16            // q blocks of 128
#define TILE_SH 12288       // shorts per (bh,kvtile) image: Khi 4096 | Klo 4096 | Vt 4096
#define IMG_B  ((size_t)NBH * NQT * TILE_SH * sizeof(short))     // 25.2 MB
#define NCH    40           // chunks per head (kv-split, <=8 tiles each)
#define OPART_B ((size_t)NBH * NCH * 128 * 64 * sizeof(float))   // 41.9 MB
#define ML_B    ((size_t)NBH * NCH * 128 * 2 * sizeof(float))    // 1.3 MB
#define WS_NEED  IMG_B
#define WS2_NEED (IMG_B + OPART_B + ML_B)

typedef __attribute__((ext_vector_type(4))) float f32x4;
typedef __attribute__((ext_vector_type(8))) short s16x8;
typedef __attribute__((ext_vector_type(4))) short s16x4;

#define MFMA_B16(A,B,C) __builtin_amdgcn_mfma_f32_16x16x32_bf16(A,B,C,0,0,0)
#define EX2(x) __builtin_amdgcn_exp2f(x)

// ---- kv-chunk map: 40 chunks/head, full-8 chunks first (i-major dispatch => heavy first)
__device__ static const int CH_QT[NCH] = {
  15,15,15,15, 14,14,14, 13,13,13, 12,12,12, 11,11,11, 10,10, 9,9, 8,8, 7,7,
  6, 5, 4, 3,            // full-8 singles
  14,10,6,2,             // len-6 partials
  13,9,5,1,              // len-4 partials
  12,8,4,0 };            // len-2 partials
__device__ static const int CH_C0[NCH] = {
  0,8,16,24, 0,8,16, 0,8,16, 0,8,16, 0,8,16, 0,8, 0,8, 0,8, 0,8,
  0, 0, 0, 0,
  24,16,8,0,
  24,16,8,0,
  24,16,8,0 };
// merge table: chunk slots per qt (-1 = none)
__device__ static const int MG[16][4] = {
  {39,-1,-1,-1},{35,-1,-1,-1},{31,-1,-1,-1},{27,-1,-1,-1},
  {26,38,-1,-1},{25,34,-1,-1},{24,30,-1,-1},{22,23,-1,-1},
  {20,21,37,-1},{18,19,33,-1},{16,17,29,-1},{13,14,15,-1},
  {10,11,12,36},{7,8,9,32},{4,5,6,28},{0,1,2,3} };

__device__ __forceinline__ short f2bf(float x){
  union{float f;unsigned u;} v; v.f=x;
  unsigned r = v.u + 0x7FFFu + ((v.u>>16)&1u);   // RNE
  return (short)(r>>16);
}
__device__ __forceinline__ float bf2f(short s){
  union{float f;unsigned u;} v; v.u=((unsigned)(unsigned short)s)<<16;
  return v.f;
}
__device__ __forceinline__ unsigned packbf(float a, float b){
  __hip_bfloat162 h = __float22bfloat162_rn(make_float2(a, b));   // v_cvt_pk_bf16_f32
  union { __hip_bfloat162 h; unsigned u; } cv; cv.h = h; return cv.u;
}
// XOR swizzle on element bits 3..5 (b128-safe)
__device__ __forceinline__ int swz(int row){
  return (((row&7) ^ ((row>>2)&7)) << 3);
}

// ---------------- pre-pass (512 thr): K -> (Khi,Klo), V -> V^T, bf16, pre-swizzled
__global__ __launch_bounds__(512) void prep_kv(
    const float* __restrict__ K, const float* __restrict__ V, short* __restrict__ W)
{
  __shared__ short Vl[4096];          // bf16 V^T image staging (8 KB)
  const int b  = blockIdx.x;          // = bh*32 + t
  const int bh = b >> 5, t = b & 31;
  const float* Kt = K + ((size_t)bh * S_LEN + t * 64) * DIM;
  const float* Vt = V + ((size_t)bh * S_LEN + t * 64) * DIM;
  short* Wt = W + (size_t)b * TILE_SH;
  const int tid = threadIdx.x;

  // --- K hi/lo: image[p] = hi/lo(K[r][(p&63)^swz(r)]) — coalesced f32x4 reads
  {
    const int r = tid >> 3, g = tid & 7;     // 512 chunks of 8 elems
    const int c0 = (g << 3) ^ swz(r);
    float x[8];
    *(f32x4*)&x[0] = *(const f32x4*)(Kt + r * DIM + c0);
    *(f32x4*)&x[4] = *(const f32x4*)(Kt + r * DIM + c0 + 4);
    s16x8 hi, lo;
#pragma unroll
    for (int j = 0; j < 8; ++j) {
      short h = f2bf(x[j]);
      hi[j] = h;
      lo[j] = f2bf(x[j] - bf2f(h));
    }
    *(s16x8*)&Wt[tid * 8]        = hi;
    *(s16x8*)&Wt[4096 + tid * 8] = lo;
  }
  // --- V: coalesced row reads -> LDS transpose -> coalesced out
  {
    const int r = tid >> 3;                 // 0..63 (row of V)
    const int cb = (tid & 7) << 3;          // 8-col chunk
    float x[8];
    *(f32x4*)&x[0] = *(const f32x4*)(Vt + r * DIM + cb);
    *(f32x4*)&x[4] = *(const f32x4*)(Vt + r * DIM + cb + 4);
#pragma unroll
    for (int j = 0; j < 8; ++j) {
      const int c = cb + j;                 // = dv
      Vl[c * 64 + (r ^ swz(c))] = f2bf(x[j]);   // image[dv*64+y] = V[y^swz(dv)][dv]
    }
  }
  __syncthreads();
  *(s16x8*)&Wt[8192 + tid * 8] = *(const s16x8*)&Vl[tid * 8];
}

// ---------------- async stage: 24KB tile image -> LDS (linear; pre-swizzled in ws)
__device__ __forceinline__ void stage24(const short* __restrict__ src, short* dst,
                                        int w, int l) {
#pragma unroll
  for (int q = 0; q < 3; ++q) {
    const int off = (q * 8 + w) << 10;            // 24 × 1KB chunks, 8 waves
    __builtin_amdgcn_global_load_lds(
        (const __attribute__((address_space(1))) unsigned*)((const char*)src + off + l * 16),
        (__attribute__((address_space(3))) unsigned*)((char*)dst + off),
        16, 0, 0);
  }
}

// ---- QK^T for one staged tile (swapped: S^T = K·Q^T), hi/lo split -> ~fp32 scores
__device__ __forceinline__ void qk_tile(f32x4 acc[4], const short* __restrict__ bK,
                                        const s16x8 qh[2], const s16x8 ql[2],
                                        int l15, int lg)
{
  const short* bKl = bK + 4096;
#pragma unroll
  for (int f = 0; f < 4; ++f) acc[f] = f32x4{0.f,0.f,0.f,0.f};
#pragma unroll
  for (int f = 0; f < 4; ++f) {
    const int kr = f * 16 + l15;
#pragma unroll
    for (int s = 0; s < 2; ++s) {
      const int dk = (((lg << 3) + (s << 5)) ^ swz(kr));
      s16x8 ah = *(const s16x8*)&bK [kr * DIM + dk];
      s16x8 al = *(const s16x8*)&bKl[kr * DIM + dk];
      acc[f] = MFMA_B16(ah, qh[s], acc[f]);
      acc[f] = MFMA_B16(ah, ql[s], acc[f]);
      acc[f] = MFMA_B16(al, qh[s], acc[f]);
    }
  }
}

// ---- online softmax on acc (scores -> p in place); updates m, lsum; rescales o
__device__ __forceinline__ void sm_update(f32x4 acc[4], f32x4 o[4], float& m, float& lsum,
                                          int kv0, int qg, int lg, float SC)
{
  const bool anymask = (kv0 + 63 > qg);
  float pm = -INFINITY;
#pragma unroll
  for (int f = 0; f < 4; ++f)
#pragma unroll
    for (int r = 0; r < 4; ++r) {
      float zz = acc[f][r] * SC;
      if (anymask && (kv0 + f * 16 + (lg << 2) + r) > qg) zz = -INFINITY;
      acc[f][r] = zz;
      pm = fmaxf(pm, zz);
    }
  pm = fmaxf(pm, __shfl_xor(pm, 16));
  pm = fmaxf(pm, __shfl_xor(pm, 32));
  if (!__all(pm <= m)) {               // rescale only when a new max appears
    const float mn = fmaxf(m, pm);
    const float al = EX2(m - mn);
    m = mn; lsum *= al;
#pragma unroll
    for (int d = 0; d < 4; ++d) o[d] *= al;
  }
  float rs = 0.f;
#pragma unroll
  for (int f = 0; f < 4; ++f)
#pragma unroll
    for (int r = 0; r < 4; ++r) {
      const float pv = EX2(acc[f][r] - m);
      acc[f][r] = pv;
      rs += pv;
    }
  rs += __shfl_xor(rs, 16);
  rs += __shfl_xor(rs, 32);
  lsum += rs;
}

// ---- P (C-frag) -> B-frag via 4-lane shuffles, then O^T += V^T·P^T
__device__ __forceinline__ void pv_tile(const f32x4 p[4], f32x4 o[4],
                                        const short* __restrict__ bVt,
                                        int l15, int lg, int src0, int src1, bool hiH)
{
  unsigned U[4][2];
#pragma unroll
  for (int f = 0; f < 4; ++f) {
    U[f][0] = packbf(p[f][0], p[f][1]);
    U[f][1] = packbf(p[f][2], p[f][3]);
  }
#pragma unroll
  for (int s = 0; s < 2; ++s) {
    unsigned a0 = __shfl(U[2*s][0], src0), a1 = __shfl(U[2*s+1][0], src0);
    unsigned b0 = __shfl(U[2*s][1], src0), b1 = __shfl(U[2*s+1][1], src0);
    unsigned c0 = __shfl(U[2*s][0], src1), c1 = __shfl(U[2*s+1][0], src1);
    unsigned d0 = __shfl(U[2*s][1], src1), d1 = __shfl(U[2*s+1][1], src1);
    union { unsigned u[4]; s16x8 v; } pb;
    pb.u[0] = hiH ? a1 : a0;
    pb.u[1] = hiH ? b1 : b0;
    pb.u[2] = hiH ? c1 : c0;
    pb.u[3] = hiH ? d1 : d0;
    const int kv8 = (lg << 3) + (s << 5);
#pragma unroll
    for (int d = 0; d < 4; ++d) {
      const int dv = d * 16 + l15;
      s16x8 vf = *(const s16x8*)&bVt[dv * DIM + (kv8 ^ swz(dv))];
      o[d] = MFMA_B16(vf, pb.v, o[d]);
    }
  }
}

// ---------------- kv-chunk kernel: 512 thr; processes tiles [c0,t1) of one q-block,
// writes UNnormalized partial O + per-row (m,l). Critical path <= 8 tile-units.
__global__ __launch_bounds__(512, 4) void fattn_chunk(
    const float* __restrict__ Qg, const short* __restrict__ W,
    float* __restrict__ Opart, float* __restrict__ ML)
{
  __shared__ __attribute__((aligned(16))) short buf[3][TILE_SH];   // 72 KB

  const int bid = blockIdx.x;           // i-major: all heads' heavy chunks first;
  const int i  = bid >> 5;              // bid%8 == bh%8 spreads heads over XCDs
  const int bh = bid & 31;
  const int qt = CH_QT[i];
  const int c0 = CH_C0[i];
  const int t1 = min(2 * qt + 2, c0 + 8);
  const int len = t1 - c0;              // 2..8 tiles

  const int tid = threadIdx.x;
  const int w = tid >> 6, l = tid & 63;
  const int l15 = l & 15, lg = l >> 4;

  const short* Wb = W + ((size_t)bh * NQT + c0) * TILE_SH;
  const float* Qb = Qg + (size_t)bh * S_LEN * DIM;

  const int row = w * 16 + l15;
  const int qg = qt * 128 + row;                  // this lane's q row
  const float SC = 0.125f * 1.44269504088896f;    // (1/sqrt(64))*log2(e)

  // ---- hoist Q fragments (hi/lo split)
  s16x8 qh[2], ql[2];
#pragma unroll
  for (int s = 0; s < 2; ++s) {
    const float* qp = Qb + (size_t)qg * DIM + (lg << 3) + s * 32;
    float qv[8];
    *(f32x4*)&qv[0] = *(const f32x4*)qp;
    *(f32x4*)&qv[4] = *(const f32x4*)(qp + 4);
#pragma unroll
    for (int j = 0; j < 8; ++j) {
      short h = f2bf(qv[j]);
      qh[s][j] = h;
      ql[s][j] = f2bf(qv[j] - bf2f(h));
    }
  }

  f32x4 o[4];
#pragma unroll
  for (int d = 0; d < 4; ++d) o[d] = f32x4{0.f,0.f,0.f,0.f};
  float m = -INFINITY, lsum = 0.f;

  const int src0 = l15 + ((lg & 1) << 5);         // P-shuffle source lanes
  const int src1 = src0 + 16;
  const bool hiH = (lg >= 2);

  // ---- pipeline prologue (len >= 2 always)
  short* b0 = buf[0];
  short* b1 = buf[1];
  short* b2 = buf[2];
  stage24(Wb, b0, w, l);
  __syncthreads();
  stage24(Wb + TILE_SH, b1, w, l);
  f32x4 acc[4];
  qk_tile(acc, b0, qh, ql, l15, lg);
  __syncthreads();

  for (int t = 0; t < len - 1; ++t) {
    if (t + 2 < len) stage24(Wb + (size_t)(t + 2) * TILE_SH, b2, w, l);
    sm_update(acc, o, m, lsum, (c0 + t) * 64, qg, lg, SC);
    f32x4 acc2[4];
    qk_tile(acc2, b1, qh, ql, l15, lg);
    pv_tile(acc, o, b0 + 8192, l15, lg, src0, src1, hiH);
#pragma unroll
    for (int f = 0; f < 4; ++f) acc[f] = acc2[f];
    short* tmp = b0; b0 = b1; b1 = b2; b2 = tmp;
    __syncthreads();
  }
  sm_update(acc, o, m, lsum, (t1 - 1) * 64, qg, lg, SC);
  pv_tile(acc, o, b0 + 8192, l15, lg, src0, src1, hiH);

  // ---- write partial (unnormalized o, plus m/l once per row)
  float* op = Opart + ((size_t)(bh * NCH + i) * 128 + row) * 64;
#pragma unroll
  for (int d = 0; d < 4; ++d)
    *(f32x4*)(op + d * 16 + (lg << 2)) = o[d];
  if (lg == 0) {
    float2 ml2 = make_float2(m, lsum);
    *(float2*)&ML[((size_t)(bh * NCH + i) * 128 + row) * 2] = ml2;
  }
}

// ---------------- merge kernel: one block per (bh,qt); combines <=4 chunk partials
__global__ __launch_bounds__(256) void fattn_merge(
    const float* __restrict__ Opart, const float* __restrict__ ML,
    float* __restrict__ Og)
{
  const int bid = blockIdx.x;
  const int qt = bid >> 5, bh = bid & 31;
  const int tid = threadIdx.x;
  const int dv4 = (tid & 15) << 2;
  const int r0  = tid >> 4;            // 0..15

#pragma unroll 1
  for (int pass = 0; pass < 8; ++pass) {
    const int row = pass * 16 + r0;
    float mv[4], lv[4];
    float M = -INFINITY;
#pragma unroll
    for (int k = 0; k < 4; ++k) { mv[k] = -INFINITY; lv[k] = 0.f; }
#pragma unroll
    for (int k = 0; k < 4; ++k) {
      const int s = MG[qt][k];
      if (s >= 0) {
        const float2 ml2 = *(const float2*)&ML[((size_t)(bh * NCH + s) * 128 + row) * 2];
        mv[k] = ml2.x; lv[k] = ml2.y;
        M = fmaxf(M, ml2.x);
      }
    }
    float L = 0.f;
    f32x4 acc = f32x4{0.f,0.f,0.f,0.f};
#pragma unroll
    for (int k = 0; k < 4; ++k) {
      const int s = MG[qt][k];
      if (s >= 0) {
        const float wgt = EX2(mv[k] - M);
        L += lv[k] * wgt;
        const f32x4 ov = *(const f32x4*)&Opart[((size_t)(bh * NCH + s) * 128 + row) * 64 + dv4];
        acc += ov * wgt;
      }
    }
    const float inv = 1.0f / L;
    f32x4 outv;
#pragma unroll
    for (int r = 0; r < 4; ++r) outv[r] = acc[r] * inv;
    *(f32x4*)(Og + ((size_t)bh * S_LEN + qt * 128 + row) * DIM + dv4) = outv;
  }
}

// ---------------- mid fallback: r9 monolithic main (ws >= IMG only) ----------------
__global__ __launch_bounds__(512, 4) void fattn_main(
    const float* __restrict__ Qg, float* __restrict__ Og, const short* __restrict__ W)
{
  __shared__ __attribute__((aligned(16))) short buf[3][TILE_SH];   // 72 KB
  const int bid = blockIdx.x;
  const int bh = bid & 31;
  const int idx = bid >> 5;
  const int qt = (idx < 8) ? (15 - idx) : (idx - 8);
  const int tid = threadIdx.x;
  const int w = tid >> 6, l = tid & 63;
  const int l15 = l & 15, lg = l >> 4;
  const short* Wb = W + (size_t)bh * NQT * TILE_SH;
  const float* Qb = Qg + (size_t)bh * S_LEN * DIM;
  float*       Ob = Og + (size_t)bh * S_LEN * DIM;
  const int qg = qt * 128 + w * 16 + l15;
  const float SC = 0.125f * 1.44269504088896f;
  s16x8 qh[2], ql[2];
#pragma unroll
  for (int s = 0; s < 2; ++s) {
    const float* qp = Qb + (size_t)qg * DIM + (lg << 3) + s * 32;
    float qv[8];
    *(f32x4*)&qv[0] = *(const f32x4*)qp;
    *(f32x4*)&qv[4] = *(const f32x4*)(qp + 4);
#pragma unroll
    for (int j = 0; j < 8; ++j) {
      short h = f2bf(qv[j]); qh[s][j] = h; ql[s][j] = f2bf(qv[j] - bf2f(h));
    }
  }
  f32x4 o[4];
#pragma unroll
  for (int d = 0; d < 4; ++d) o[d] = f32x4{0.f,0.f,0.f,0.f};
  float m = -INFINITY, lsum = 0.f;
  const int src0 = l15 + ((lg & 1) << 5);
  const int src1 = src0 + 16;
  const bool hiH = (lg >= 2);
  const int nt = 2 * qt + 2;
  short* b0 = buf[0]; short* b1 = buf[1]; short* b2 = buf[2];
  stage24(Wb, b0, w, l);
  __syncthreads();
  stage24(Wb + TILE_SH, b1, w, l);
  f32x4 acc[4];
  qk_tile(acc, b0, qh, ql, l15, lg);
  __syncthreads();
  for (int t = 0; t < nt - 1; ++t) {
    if (t + 2 < nt) stage24(Wb + (size_t)(t + 2) * TILE_SH, b2, w, l);
    sm_update(acc, o, m, lsum, t * 64, qg, lg, SC);
    f32x4 acc2[4];
    qk_tile(acc2, b1, qh, ql, l15, lg);
    pv_tile(acc, o, b0 + 8192, l15, lg, src0, src1, hiH);
#pragma unroll
    for (int f = 0; f < 4; ++f) acc[f] = acc2[f];
    short* tmp = b0; b0 = b1; b1 = b2; b2 = tmp;
    __syncthreads();
  }
  sm_update(acc, o, m, lsum, (nt - 1) * 64, qg, lg, SC);
  pv_tile(acc, o, b0 + 8192, l15, lg, src0, src1, hiH);
  const float inv = 1.0f / lsum;
#pragma unroll
  for (int d = 0; d < 4; ++d) {
    f32x4 ov;
#pragma unroll
    for (int r = 0; r < 4; ++r) ov[r] = o[d][r] * inv;
    *(f32x4*)(Ob + (size_t)qg * DIM + d * 16 + (lg << 2)) = ov;
  }
}

// ---------------- last-resort fallback (no ws): round-1 kernel ----------------
#define QBLK  64
#define KVBLK 64
#define NPAIR (NQT/2)
#define NBLK  (NBH*NPAIR)

__global__ __launch_bounds__(256) void fattn_fb(
    const float* __restrict__ Qg, const float* __restrict__ Kg,
    const float* __restrict__ Vg, float* __restrict__ Og)
{
  __shared__ __attribute__((aligned(16))) short Khi[KVBLK*DIM];
  __shared__ __attribute__((aligned(16))) short Klo[KVBLK*DIM];
  __shared__ __attribute__((aligned(16))) short Vt [DIM*KVBLK];
  __shared__ __attribute__((aligned(16))) short Pl [4*16*KVBLK];
  int bid0 = blockIdx.x;
  int bid  = (bid0 & 7) * (NBLK/8) + (bid0 >> 3);
  int bh   = bid / NPAIR;
  int pr   = bid % NPAIR;
  const int tid = threadIdx.x;
  const int w = tid >> 6, l = tid & 63, l15 = l & 15, lg = l >> 4;
  const float* Qb = Qg + (size_t)bh * S_LEN * DIM;
  const float* Kb = Kg + (size_t)bh * S_LEN * DIM;
  const float* Vb = Vg + (size_t)bh * S_LEN * DIM;
  float*       Ob = Og + (size_t)bh * S_LEN * DIM;
  const float SC = 0.125f * 1.44269504088896f;
  for (int half = 0; half < 2; ++half) {
    const int qt = half ? (NQT - 1 - pr) : pr;
    const int qg = qt * QBLK + w * 16 + l15;
    s16x8 qh[2], ql[2];
#pragma unroll
    for (int s = 0; s < 2; ++s) {
      const float* qp = Qb + (size_t)qg * DIM + (lg << 3) + s * 32;
      float qv[8];
      *(f32x4*)&qv[0] = *(const f32x4*)qp;
      *(f32x4*)&qv[4] = *(const f32x4*)(qp + 4);
#pragma unroll
      for (int j = 0; j < 8; ++j) {
        short h = f2bf(qv[j]); qh[s][j] = h; ql[s][j] = f2bf(qv[j] - bf2f(h));
      }
    }
    f32x4 o[4];
#pragma unroll
    for (int d = 0; d < 4; ++d) o[d] = f32x4{0.f,0.f,0.f,0.f};
    float m = -INFINITY, lsum = 0.f;
    const int ntiles = qt + 1;
    for (int t = 0; t < ntiles; ++t) {
      const int kv0 = t * KVBLK;
      __syncthreads();
      {
        const int row = tid >> 4, c4 = (tid & 15) << 2;
#pragma unroll
        for (int i = 0; i < 4; ++i) {
          const int r = row + (i << 4);
          const f32x4 kv4 = *(const f32x4*)(Kb + (size_t)(kv0 + r) * DIM + c4);
          const f32x4 vv4 = *(const f32x4*)(Vb + (size_t)(kv0 + r) * DIM + c4);
          const int cs = c4 ^ swz(r);
          s16x4 kh, kl;
#pragma unroll
          for (int j = 0; j < 4; ++j) { short h = f2bf(kv4[j]); kh[j] = h; kl[j] = f2bf(kv4[j] - bf2f(h)); }
          *(s16x4*)&Khi[r * DIM + cs] = kh;
          *(s16x4*)&Klo[r * DIM + cs] = kl;
#pragma unroll
          for (int j = 0; j < 4; ++j) { const int dv = c4 + j; Vt[dv * KVBLK + (r ^ swz(dv))] = f2bf(vv4[j]); }
        }
      }
      __syncthreads();
      f32x4 acc[4];
#pragma unroll
      for (int f = 0; f < 4; ++f) acc[f] = f32x4{0.f,0.f,0.f,0.f};
#pragma unroll
      for (int f = 0; f < 4; ++f) {
        const int kr = f * 16 + l15;
#pragma unroll
        for (int s = 0; s < 2; ++s) {
          const int dk = (((lg << 3) + (s << 5)) ^ swz(kr));
          s16x8 ah = *(const s16x8*)&Khi[kr * DIM + dk];
          s16x8 al = *(const s16x8*)&Klo[kr * DIM + dk];
          acc[f] = MFMA_B16(ah, qh[s], acc[f]);
          acc[f] = MFMA_B16(ah, ql[s], acc[f]);
          acc[f] = MFMA_B16(al, qh[s], acc[f]);
        }
      }
      const bool diag = (t == qt);
      float z[4][4];
#pragma unroll
      for (int f = 0; f < 4; ++f)
#pragma unroll
        for (int r = 0; r < 4; ++r) {
          float zz = acc[f][r] * SC;
          if (diag && (kv0 + f * 16 + (lg << 2) + r) > qg) zz = -INFINITY;
          z[f][r] = zz;
        }
      float pm = z[0][0];
#pragma unroll
      for (int f = 0; f < 4; ++f)
#pragma unroll
        for (int r = 0; r < 4; ++r) pm = fmaxf(pm, z[f][r]);
      pm = fmaxf(pm, __shfl_xor(pm, 16));
      pm = fmaxf(pm, __shfl_xor(pm, 32));
      const float mn = fmaxf(m, pm);
      const float alpha = EX2(m - mn);
      float p[4][4]; float rs = 0.f;
#pragma unroll
      for (int f = 0; f < 4; ++f)
#pragma unroll
        for (int r = 0; r < 4; ++r) { const float pv = EX2(z[f][r] - mn); p[f][r] = pv; rs += pv; }
      rs += __shfl_xor(rs, 16);
      rs += __shfl_xor(rs, 32);
      lsum = lsum * alpha + rs;
      m = mn;
#pragma unroll
      for (int d = 0; d < 4; ++d) o[d] *= alpha;
      short* Pw = &Pl[w * 16 * KVBLK];
#pragma unroll
      for (int f = 0; f < 4; ++f) {
        s16x4 pk;
#pragma unroll
        for (int r = 0; r < 4; ++r) pk[r] = f2bf(p[f][r]);
        const int kvc = (f * 16 + (lg << 2)) ^ swz(l15);
        *(s16x4*)&Pw[l15 * KVBLK + kvc] = pk;
      }
#pragma unroll
      for (int s = 0; s < 2; ++s) {
        const int kv8 = (lg << 3) + s * 32;
        s16x8 pf = *(const s16x8*)&Pw[l15 * KVBLK + (kv8 ^ swz(l15))];
#pragma unroll
        for (int d = 0; d < 4; ++d) {
          const int dv = d * 16 + l15;
          s16x8 vf = *(const s16x8*)&Vt[dv * KVBLK + (kv8 ^ swz(dv))];
          o[d] = MFMA_B16(vf, pf, o[d]);
        }
      }
    }
    const float inv = 1.0f / lsum;
#pragma unroll
    for (int d = 0; d < 4; ++d) {
      f32x4 ov;
#pragma unroll
      for (int r = 0; r < 4; ++r) ov[r] = o[d][r] * inv;
      *(f32x4*)(Ob + (size_t)qg * DIM + d * 16 + (lg << 2)) = ov;
    }
  }
}

extern "C" void kernel_launch(void* const* d_in, const int* in_sizes, int n_in,
                              void* d_out, int out_size, void* d_ws, size_t ws_size,
                              hipStream_t stream) {
  const float* Q = (const float*)d_in[0];
  const float* K = (const float*)d_in[1];
  const float* V = (const float*)d_in[2];
  float* O = (float*)d_out;
  if (ws_size >= WS2_NEED) {
    short* W      = (short*)d_ws;
    float* Opart  = (float*)((char*)d_ws + IMG_B);
    float* ML     = Opart + (size_t)NBH * NCH * 128 * 64;
    prep_kv    <<<dim3(NBH * NQT), dim3(512), 0, stream>>>(K, V, W);
    fattn_chunk<<<dim3(NBH * NCH), dim3(512), 0, stream>>>(Q, W, Opart, ML);
    fattn_merge<<<dim3(NBH * NQB), dim3(256), 0, stream>>>(Opart, ML, O);
  } else if (ws_size >= WS_NEED) {
    short* W = (short*)d_ws;
    prep_kv  <<<dim3(NBH * NQT), dim3(512), 0, stream>>>(K, V, W);
    fattn_main<<<dim3(NBH * NQB), dim3(512), 0, stream>>>(Q, O, W);
  } else {
    fattn_fb<<<dim3(NBLK), dim3(256), 0, stream>>>(Q, K, V, O);
  }
}